// Round 9
// baseline (196.244 us; speedup 1.0000x reference)
//
#include <hip/hip_runtime.h>
#include <cstdint>
#include <cstddef>

namespace {

constexpr int kC = 512;
constexpr int kHW = 4096;            // H*W = 64*64
constexpr int kHeads = 8;
constexpr int kChunkElems = 64 * 64; // tokens per chunk * head dim

typedef float f32x4 __attribute__((ext_vector_type(4)));
typedef _Float16 f16x8 __attribute__((ext_vector_type(8)));
union FragU { uint4 u; f16x8 h; };

__device__ __forceinline__ ushort f16rn(float x) {
  _Float16 h = (_Float16)x;           // v_cvt_f16_f32, RNE
  ushort u;
  __builtin_memcpy(&u, &h, 2);
  return u;
}
__device__ __forceinline__ uint pack2(ushort a, ushort b) {
  return (uint)a | ((uint)b << 16);
}
__device__ __forceinline__ float fexp2(float x) {
  return exp2f(x);   // folds to v_exp_f32 under -O3 on gfx950
}
__device__ __forceinline__ uint pkrtz(float a, float b) {
  // v_cvt_pkrtz_f16_f32: two f32 -> packed f16x2, round-toward-zero.
  auto h = __builtin_amdgcn_cvt_pkrtz(a, b);
  uint u;
  __builtin_memcpy(&u, &h, 4);
  return u;
}
__device__ __forceinline__ void gld16(const void* g, void* lds) {
  __builtin_amdgcn_global_load_lds(
      (const __attribute__((address_space(1))) uint32_t*)g,
      (__attribute__((address_space(3))) uint32_t*)lds, 16, 0, 0);
}

// ---------------------------------------------------------------------------
// Kernel W16: single-plane f16 weight conversion (qkv AND proj weights).
// n elems must be multiple of 2048 (grid = n/2048).
// ---------------------------------------------------------------------------
__global__ __launch_bounds__(256)
void convw16_kernel(const float* __restrict__ w, ushort* __restrict__ wh)
{
  int idx = (blockIdx.x * 256 + threadIdx.x) * 8;
  float4 v0 = *(const float4*)(w + idx);
  float4 v1 = *(const float4*)(w + idx + 4);
  float xs[8] = {v0.x, v0.y, v0.z, v0.w, v1.x, v1.y, v1.z, v1.w};
  ushort hh[8];
#pragma unroll
  for (int e = 0; e < 8; ++e) hh[e] = f16rn(xs[e]);
  *(uint4*)(wh + idx) = make_uint4(pack2(hh[0], hh[1]), pack2(hh[2], hh[3]),
                                   pack2(hh[4], hh[5]), pack2(hh[6], hh[7]));
}

// ---------------------------------------------------------------------------
// Kernel 0: transpose + f16 x:  [b][c][t] fp32 -> xt [b][t][c] (f16 plane)
// ---------------------------------------------------------------------------
__global__ __launch_bounds__(256)
void convx_kernel(const float* __restrict__ x, ushort* __restrict__ xt)
{
  __shared__ float LT[64][68];
  const int tid = threadIdx.x;
  const int t0 = blockIdx.x * 64;
  const int c0 = blockIdx.y * 64;
  const int b  = blockIdx.z;
  const float* xb = x + (size_t)b * kC * kHW;

#pragma unroll
  for (int u = 0; u < 4; ++u) {
    int idx = tid + u * 256;
    int rc = idx >> 4;
    int t4 = (idx & 15) << 2;
    float4 val = *(const float4*)(xb + (size_t)(c0 + rc) * kHW + t0 + t4);
    LT[t4 + 0][rc] = val.x;
    LT[t4 + 1][rc] = val.y;
    LT[t4 + 2][rc] = val.z;
    LT[t4 + 3][rc] = val.w;
  }
  __syncthreads();
#pragma unroll
  for (int u = 0; u < 4; ++u) {
    int idx = tid + u * 256;
    int rt = idx >> 4;
    int c4 = (idx & 15) << 2;
    float4 v = *(const float4*)&LT[rt][c4];
    size_t o = ((size_t)b * kHW + t0 + rt) * kC + c0 + c4;
    *(ushort4*)(xt + o) = make_ushort4(f16rn(v.x), f16rn(v.y),
                                       f16rn(v.z), f16rn(v.w));
  }
}

// ---------------------------------------------------------------------------
// Kernel 1: QKV GEMM, 256x128 tile, 8 waves (4M x 2N), BK=64, 96KB LDS,
// double-buffered staging with read-ahead frag pipelining + setprio.
// One barrier per K-step; stage(t+1) issued at top (covered by compute).
// Bijective XCD swizzle (768 blocks, 96/XCD) for L2 panel reuse.
// q scale folds log2e so attn softmax uses bare exp2.
// ---------------------------------------------------------------------------
__global__ __launch_bounds__(512)
void qkv_mfma_kernel(const ushort* __restrict__ xt,
                     const ushort* __restrict__ wq,
                     const float* __restrict__ bqkv,
                     ushort* __restrict__ qo, ushort* __restrict__ ko,
                     ushort* __restrict__ vo)
{
  __shared__ __align__(16) ushort As[2][256 * 64];   // x, 32KB each
  __shared__ __align__(16) ushort Bs[2][128 * 64];   // w, 16KB each

  const int tid  = threadIdx.x;
  const int lane = tid & 63;
  const int wv   = tid >> 6;          // 0..7
  const int quad = lane >> 4;
  const int l15  = lane & 15;
  const int wm = wv & 3;              // 0..3 (M quadrant, 64 rows each)
  const int wn = wv >> 2;             // 0..1 (N half, 64 cols each)

  // bijective XCD swizzle: 768 blocks -> 96 contiguous work-items per XCD
  const int flat = blockIdx.x + 16 * (blockIdx.y + 12 * blockIdx.z);
  const int swz  = (flat & 7) * 96 + (flat >> 3);
  const int m0 = (swz & 15) * 256;    // 16 m-tiles
  const int t2 = swz >> 4;            // 0..47
  const int n0 = (t2 % 12) * 128;     // 12 n-tiles
  const int b  = t2 / 12;             // 4 batches

  const ushort* xb = xt + (size_t)b * kHW * kC;

  auto stage = [&](int buf, int k0) {
#pragma unroll
    for (int ii = 0; ii < 4; ++ii) {
      int i = wv * 4 + ii;                 // 32 x 1KB A pieces
      int m = i * 8 + (lane >> 3);
      int gch = (lane & 7) ^ (m & 7);      // swizzled 16B chunk within row
      gld16(xb + (size_t)(m0 + m) * kC + k0 + gch * 8,
            (char*)&As[buf][0] + i * 1024);
    }
#pragma unroll
    for (int ii = 0; ii < 2; ++ii) {
      int i = wv * 2 + ii;                 // 16 x 1KB B pieces
      int m = i * 8 + (lane >> 3);
      int gch = (lane & 7) ^ (m & 7);
      gld16(wq + (size_t)(n0 + m) * kC + k0 + gch * 8,
            (char*)&Bs[buf][0] + i * 1024);
    }
  };

  f32x4 acc[4][4];
#pragma unroll
  for (int i = 0; i < 4; ++i)
#pragma unroll
    for (int j = 0; j < 4; ++j) acc[i][j] = (f32x4){0.f, 0.f, 0.f, 0.f};

  stage(0, 0);
  asm volatile("s_waitcnt vmcnt(0)" ::: "memory");
  asm volatile("s_barrier" ::: "memory");

  for (int kt = 0; kt < 8; ++kt) {
    const int cur = kt & 1;
    if (kt < 7) stage(cur ^ 1, (kt + 1) * 64);   // covered by compute below

    const ushort* Ac = &As[cur][0];
    const ushort* Bc = &Bs[cur][0];
    // read-ahead both k-halves' fragments; compiler interleaves the second
    // batch's ds_reads under the first MFMA cluster via counted lgkmcnt.
    FragU a0[4], a1[4], b0[4], b1[4];
#pragma unroll
    for (int mi = 0; mi < 4; ++mi) {
      int mr = wm * 64 + mi * 16 + l15;
      int sw = mr & 7;
      a0[mi].u = *(const uint4*)&Ac[mr * 64 + ((quad ^ sw) * 8)];
      a1[mi].u = *(const uint4*)&Ac[mr * 64 + (((4 + quad) ^ sw) * 8)];
    }
#pragma unroll
    for (int ni = 0; ni < 4; ++ni) {
      int nr = wn * 64 + ni * 16 + l15;
      int sw = nr & 7;
      b0[ni].u = *(const uint4*)&Bc[nr * 64 + ((quad ^ sw) * 8)];
      b1[ni].u = *(const uint4*)&Bc[nr * 64 + (((4 + quad) ^ sw) * 8)];
    }
    __builtin_amdgcn_s_setprio(1);
#pragma unroll
    for (int mi = 0; mi < 4; ++mi)
#pragma unroll
      for (int ni = 0; ni < 4; ++ni)
        acc[mi][ni] = __builtin_amdgcn_mfma_f32_16x16x32_f16(a0[mi].h, b0[ni].h, acc[mi][ni], 0, 0, 0);
#pragma unroll
    for (int mi = 0; mi < 4; ++mi)
#pragma unroll
      for (int ni = 0; ni < 4; ++ni)
        acc[mi][ni] = __builtin_amdgcn_mfma_f32_16x16x32_f16(a1[mi].h, b1[ni].h, acc[mi][ni], 0, 0, 0);
    __builtin_amdgcn_s_setprio(0);

    asm volatile("s_waitcnt lgkmcnt(0)" ::: "memory");  // my reads of cur done
    if (kt < 7) asm volatile("s_waitcnt vmcnt(0)" ::: "memory");  // next buf in
    asm volatile("s_barrier" ::: "memory");
  }

  // ---- epilogue ----
  const int sec = n0 >> 9;                 // block-uniform: 0=q,1=k,2=v
  const int jwbase = n0 + wn * 64;         // 64-aligned -> head fixed per wave
  const int head = (jwbase >> 6) & 7;
  const size_t hbb = ((size_t)b * kHeads + head) * 64;
  float biasv[4];
#pragma unroll
  for (int ni = 0; ni < 4; ++ni) biasv[ni] = bqkv[jwbase + ni * 16 + l15];

  if (sec == 2) {
    // v: transposed [dd][tok]; lane's 4 acc rows are 4 consecutive toks
#pragma unroll
    for (int ni = 0; ni < 4; ++ni) {
      int dd = ni * 16 + l15;
#pragma unroll
      for (int mi = 0; mi < 4; ++mi) {
        int t0t = m0 + wm * 64 + mi * 16 + quad * 4;
        int h = t0t >> 6, w = t0t & 63;
        int cy = h >> 3, iy = h & 7, cx = w >> 3, ix = w & 7;
        size_t cb = (hbb + cy * 8 + cx) * (size_t)kChunkElems;
        int tokb = iy * 8 + ix;
        ushort hh[4];
#pragma unroll
        for (int r = 0; r < 4; ++r) hh[r] = f16rn(acc[mi][ni][r] + biasv[ni]);
        *(ushort4*)(vo + cb + (size_t)dd * 64 + tokb) = make_ushort4(hh[0], hh[1], hh[2], hh[3]);
      }
    }
  } else {
    // q/k: per-wave-private LDS transpose -> vectorized uint4 stores.
    // scratch in As[0] (all LDS free after the loop's final barrier);
    // 8 waves x 1152 ushorts = 18KB <= 32KB.
    ushort* dst = (sec == 0) ? qo : ko;
    // q pre-scaled by 1/8 (d^-1/2) AND log2e so attn uses exp2 directly.
    const float sc = (sec == 0) ? 0.125f * 1.44269504089f : 1.0f;
    ushort* tH = &As[0][0] + wv * 1152;
    const int ltok = lane >> 2;
    const int dd0 = (lane & 3) * 16;
#pragma unroll
    for (int mi = 0; mi < 4; ++mi) {
#pragma unroll
      for (int ni = 0; ni < 4; ++ni)
#pragma unroll
        for (int r = 0; r < 4; ++r)
          tH[(quad * 4 + r) * 68 + ni * 16 + l15] =
              f16rn((acc[mi][ni][r] + biasv[ni]) * sc);
      int tg = m0 + wm * 64 + mi * 16 + ltok;
      int h = tg >> 6, w = tg & 63;
      int cy = h >> 3, iy = h & 7, cx = w >> 3, ix = w & 7;
      size_t cb = (hbb + cy * 8 + cx) * (size_t)kChunkElems
                + (size_t)(iy * 8 + ix) * 64 + dd0;
      uint4 h0 = *(const uint4*)&tH[ltok * 68 + dd0];
      uint4 h1 = *(const uint4*)&tH[ltok * 68 + dd0 + 8];
      *(uint4*)(dst + cb) = h0;
      *(uint4*)(dst + cb + 8) = h1;
    }
  }
}

// ---------------------------------------------------------------------------
// Kernel 2: MFMA flash attention (swapped-operand, split-staged schedule,
// VALU-minimized, single f16 ao plane). Unchanged from r8.
// ---------------------------------------------------------------------------
__global__ __launch_bounds__(256)
void attn_mfma_kernel(const ushort* __restrict__ qg, const ushort* __restrict__ kg,
                      const ushort* __restrict__ vg,
                      ushort* __restrict__ ao)
{
  __shared__ __align__(16) ushort KB[4096], VB[4096];  // 8KB each
  __shared__ __align__(16) ushort Ps[4 * 16 * 72];     // per-wave 16x72

  const int tid  = threadIdx.x;
  const int lane = tid & 63;
  const int wv   = tid >> 6;
  const int quad = lane >> 4;
  const int l15  = lane & 15;

  // XCD-aware swizzle: group g (b,head) pinned to XCD bx&7 (4 groups/XCD).
  const int bx = blockIdx.x;
  const int g  = (bx & 7) * 4 + ((bx >> 3) >> 6);  // 0..31
  const int c  = (bx >> 3) & 63;                   // chunk in group
  const int b = g >> 3, head = g & 7;
  const int cy = c >> 3, cx = c & 7;

  const size_t hb = (size_t)b * kHeads + head;
  const size_t gbase = hb * 64 * (size_t)kChunkElems;   // group base
  const size_t cbase = gbase + (size_t)c * (size_t)kChunkElems;

  FragU aQ0, aQ1;
  {
    const ushort* qr = qg + cbase + (size_t)(wv * 16 + l15) * 64 + quad * 8;
    aQ0.u = *(const uint4*)(qr);
    aQ1.u = *(const uint4*)(qr + 32);
  }

  // per-lane staging bases (include boff + wave piece offset)
  const int boff = ((lane >> 3) * 64) + (((lane & 7) ^ (lane >> 3)) * 8);
  const ushort* kgB = kg + gbase + boff + (size_t)(wv * 2) * 512;
  const ushort* vgB = vg + gbase + boff + (size_t)(wv * 2) * 512;
  char* kDst0 = (char*)KB + (wv * 2) * 1024;
  char* vDst0 = (char*)VB + (wv * 2) * 1024;

  // hoisted K/V LDS fragment offsets (loop-invariant)
  int kvOff0[4], kvOff1[4];
  {
    const int sw = l15 & 7;
#pragma unroll
    for (int nt = 0; nt < 4; ++nt) {
      int row = nt * 16 + l15;
      kvOff0[nt] = row * 64 + ((quad ^ sw) * 8);
      kvOff1[nt] = row * 64 + (((4 + quad) ^ sw) * 8);
    }
  }

  ushort* PsW = Ps + wv * 1152;          // per-wave 16 x 72
  ushort* pWr = PsW + l15 * 72 + quad * 4;
  const ushort* pRd = PsW + l15 * 72 + quad * 8;

  // packed valid-neighbor chunk list (block-uniform -> SALU)
  unsigned long long list = 0ull;
  int cnt = 0;
#pragma unroll
  for (int p = 0; p < 9; ++p) {
    const int dy = p / 3 - 1, dx = p % 3 - 1;   // compile-time constants
    int ny = cy + dy, nx = cx + dx;
    if ((unsigned)ny < 8u && (unsigned)nx < 8u) {
      list |= (unsigned long long)(ny * 8 + nx) << (6 * cnt);
      ++cnt;
    }
  }

  f32x4 o[4];
#pragma unroll
  for (int r = 0; r < 4; ++r) o[r] = (f32x4){0.f, 0.f, 0.f, 0.f};
  float rsum = 0.f;

  {
    int ch0 = (int)(list & 63);
    const ushort* pk = kgB + (size_t)ch0 * kChunkElems;
    gld16(pk, kDst0);
    gld16(pk + 512, kDst0 + 1024);
    const ushort* pv = vgB + (size_t)ch0 * kChunkElems;
    gld16(pv, vDst0);
    gld16(pv + 512, vDst0 + 1024);
  }

  for (int i = 0; i < cnt; ++i) {
    const bool more = (i + 1 < cnt);
    const int chn = (int)((list >> (6 * (i + 1))) & 63);  // unused if !more

    // top: own K(i) landed (V(i) may still be in flight)
    asm volatile("s_waitcnt vmcnt(2)" ::: "memory");
    asm volatile("s_barrier" ::: "memory");   // KB valid for all waves

    FragU kf[8];
#pragma unroll
    for (int nt = 0; nt < 4; ++nt) {
      kf[nt * 2].u     = *(const uint4*)&KB[kvOff0[nt]];
      kf[nt * 2 + 1].u = *(const uint4*)&KB[kvOff1[nt]];
    }
    asm volatile("s_waitcnt lgkmcnt(0)" ::: "memory");  // K frags in regs
    asm volatile("s_waitcnt vmcnt(0)" ::: "memory");    // own V(i) landed
    asm volatile("s_barrier" ::: "memory");   // KB free, VB valid for all

    if (more) {
      const ushort* pk = kgB + (size_t)chn * kChunkElems;
      gld16(pk, kDst0);
      gld16(pk + 512, kDst0 + 1024);
    }

    // S^T = K * Q^T : lane -> S[key = nt*16 + quad*4 + r][q = l15]
    f32x4 s[4];
#pragma unroll
    for (int nt = 0; nt < 4; ++nt) s[nt] = (f32x4){0.f, 0.f, 0.f, 0.f};
#pragma unroll
    for (int nt = 0; nt < 4; ++nt) {
      s[nt] = __builtin_amdgcn_mfma_f32_16x16x32_f16(kf[nt * 2].h, aQ0.h, s[nt], 0, 0, 0);
      s[nt] = __builtin_amdgcn_mfma_f32_16x16x32_f16(kf[nt * 2 + 1].h, aQ1.h, s[nt], 0, 0, 0);
    }

    // P = exp2(S') (log2e pre-folded into q); pack via cvt_pkrtz; b64 store
#pragma unroll
    for (int nt = 0; nt < 4; ++nt) {
      float e0 = fexp2(s[nt][0]);
      float e1 = fexp2(s[nt][1]);
      float e2 = fexp2(s[nt][2]);
      float e3 = fexp2(s[nt][3]);
      rsum += (e0 + e1) + (e2 + e3);
      *(uint2*)(pWr + nt * 16) = make_uint2(pkrtz(e0, e1), pkrtz(e2, e3));
    }

    FragU aP0, aP1;
    aP0.u = *(const uint4*)(pRd);
    aP1.u = *(const uint4*)(pRd + 32);

    // O^T = V^T * P^T : lane -> O[q = l15][dd = nt*16 + quad*4 + r]
#pragma unroll
    for (int nt = 0; nt < 4; ++nt) {
      FragU v0, v1;
      v0.u = *(const uint4*)&VB[kvOff0[nt]];
      v1.u = *(const uint4*)&VB[kvOff1[nt]];
      o[nt] = __builtin_amdgcn_mfma_f32_16x16x32_f16(v0.h, aP0.h, o[nt], 0, 0, 0);
      o[nt] = __builtin_amdgcn_mfma_f32_16x16x32_f16(v1.h, aP1.h, o[nt], 0, 0, 0);
    }

    asm volatile("s_waitcnt lgkmcnt(0)" ::: "memory");  // V reads drained
    asm volatile("s_barrier" ::: "memory");   // VB free
    if (more) {
      const ushort* pv = vgB + (size_t)chn * kChunkElems;
      gld16(pv, vDst0);
      gld16(pv + 512, vDst0 + 1024);
    }
  }

  // ---- row-sum reduce across the 4 quad partners (q = l15 fixed per lane)
  rsum += __shfl_xor(rsum, 16, 64);
  rsum += __shfl_xor(rsum, 32, 64);
  const float inv = 1.0f / rsum;

  // ---- epilogue: lane holds one token's row (q = wv*16 + l15); store ao
  // as a single f16 plane straight from registers, 8B per nt.
  const int trg = wv * 16 + l15;
  const int hp = cy * 8 + (trg >> 3);
  const int wp = cx * 8 + (trg & 7);
  const size_t obase = ((size_t)b * kHW + hp * 64 + wp) * (size_t)kC + head * 64;

#pragma unroll
  for (int nt = 0; nt < 4; ++nt) {
    float v0 = o[nt][0] * inv;
    float v1 = o[nt][1] * inv;
    float v2 = o[nt][2] * inv;
    float v3 = o[nt][3] * inv;
    *(ushort4*)(ao + obase + nt * 16 + quad * 4) =
        make_ushort4(f16rn(v0), f16rn(v1), f16rn(v2), f16rn(v3));
  }
}

// ---------------------------------------------------------------------------
// Kernel 3: output projection, single-plane f16 MFMA, double-buffered
// staging (unchanged from r8). LDS 48KB -> 3 blocks/CU.
// ---------------------------------------------------------------------------
__global__ __launch_bounds__(256)
void proj_mfma_kernel(const ushort* __restrict__ ao,
                      const ushort* __restrict__ wp,
                      const float* __restrict__ bproj,
                      float* __restrict__ out)
{
  __shared__ __align__(16) ushort As[2][128 * 64];   // wproj 16KB each
  __shared__ __align__(16) ushort Bs[2][64 * 64];    // ao 8KB each

  const int tid  = threadIdx.x;
  const int lane = tid & 63;
  const int wv   = tid >> 6;
  const int quad = lane >> 4;
  const int l15  = lane & 15;
  const int wm = wv & 1, wn = wv >> 1;
  const int n0g = blockIdx.x * 64;    // global t (batch-fused, 0..16383)
  const int m0  = blockIdx.y * 128;   // c
  const int b   = n0g >> 12;
  const int tl0 = n0g & 4095;

  auto stage = [&](int buf, int k0) {
#pragma unroll
    for (int ii = 0; ii < 4; ++ii) {
      int i = wv * 4 + ii;
      int m = i * 8 + (lane >> 3);
      int gch = (lane & 7) ^ (m & 7);
      size_t goA = (size_t)(m0 + m) * kC + k0 + gch * 8;
      gld16(wp + goA, (char*)&As[buf][0] + i * 1024);
    }
#pragma unroll
    for (int ii = 0; ii < 2; ++ii) {
      int i = wv * 2 + ii;
      int m = i * 8 + (lane >> 3);
      int gch = (lane & 7) ^ (m & 7);
      size_t goB = (size_t)(n0g + m) * kC + k0 + gch * 8;
      gld16(ao + goB, (char*)&Bs[buf][0] + i * 1024);
    }
  };

  f32x4 acc[4][2];
#pragma unroll
  for (int i = 0; i < 4; ++i)
#pragma unroll
    for (int j = 0; j < 2; ++j) acc[i][j] = (f32x4){0.f, 0.f, 0.f, 0.f};

  stage(0, 0);
  asm volatile("s_waitcnt vmcnt(0)" ::: "memory");
  asm volatile("s_barrier" ::: "memory");

  for (int kt = 0; kt < 8; ++kt) {
    const int cur = kt & 1;
    if (kt < 7) stage(cur ^ 1, (kt + 1) * 64);

    const ushort* Ac = &As[cur][0];
    const ushort* Bc = &Bs[cur][0];
#pragma unroll
    for (int s = 0; s < 2; ++s) {
      const int gq = s * 4 + quad;
      FragU aA[4], bB[2];
#pragma unroll
      for (int mi = 0; mi < 4; ++mi) {
        int mr = wm * 64 + mi * 16 + l15;
        int off = mr * 64 + ((gq ^ (mr & 7)) * 8);
        aA[mi].u = *(const uint4*)&Ac[off];
      }
#pragma unroll
      for (int ni = 0; ni < 2; ++ni) {
        int nr = wn * 32 + ni * 16 + l15;
        int off = nr * 64 + ((gq ^ (nr & 7)) * 8);
        bB[ni].u = *(const uint4*)&Bc[off];
      }
#pragma unroll
      for (int mi = 0; mi < 4; ++mi)
#pragma unroll
        for (int ni = 0; ni < 2; ++ni)
          acc[mi][ni] = __builtin_amdgcn_mfma_f32_16x16x32_f16(aA[mi].h, bB[ni].h, acc[mi][ni], 0, 0, 0);
    }

    asm volatile("s_waitcnt lgkmcnt(0)" ::: "memory");
    if (kt < 7) asm volatile("s_waitcnt vmcnt(0)" ::: "memory");
    asm volatile("s_barrier" ::: "memory");
  }

#pragma unroll
  for (int mi = 0; mi < 4; ++mi)
#pragma unroll
    for (int r = 0; r < 4; ++r) {
      int c = m0 + wm * 64 + mi * 16 + quad * 4 + r;
      float bias = bproj[c];
      size_t rowb = ((size_t)b * kC + c) * (size_t)kHW + tl0 + wn * 32;
#pragma unroll
      for (int ni = 0; ni < 2; ++ni)
        out[rowb + ni * 16 + l15] = acc[mi][ni][r] + bias;
    }
}

}  // namespace

extern "C" void kernel_launch(void* const* d_in, const int* in_sizes, int n_in,
                              void* d_out, int out_size, void* d_ws, size_t ws_size,
                              hipStream_t stream)
{
  const float* x     = (const float*)d_in[0];
  const float* wqkv  = (const float*)d_in[1];
  const float* bqkv  = (const float*)d_in[2];
  const float* wproj = (const float*)d_in[3];
  const float* bproj = (const float*)d_in[4];
  float* out = (float*)d_out;

  const size_t seg = (size_t)2048 * kChunkElems;  // 8,388,608 elems
  ushort* base = (ushort*)d_ws;
  ushort* qb = base + 0 * seg;
  ushort* kb = base + 1 * seg;
  ushort* vb = base + 2 * seg;
  ushort* xt = base + 3 * seg;
  ushort* ao = xt;                       // alias (xt dead after qkv GEMM)
  ushort* wqh = base + 5 * seg;          // 1536*512 = 786432 elems (f16)
  ushort* wp16 = qb;                     // alias over dead q-plane (512*512)

  convw16_kernel<<<dim3(384), 256, 0, stream>>>(wqkv, wqh);
  convx_kernel<<<dim3(64, 8, 4), 256, 0, stream>>>(x, xt);
  qkv_mfma_kernel<<<dim3(16, 12, 4), 512, 0, stream>>>(xt, wqh, bqkv,
                                                       qb, kb, vb);
  attn_mfma_kernel<<<dim3(2048), 256, 0, stream>>>(qb, kb, vb, ao);
  convw16_kernel<<<dim3(128), 256, 0, stream>>>(wproj, wp16);
  proj_mfma_kernel<<<dim3(256, 4), 256, 0, stream>>>(ao, wp16, bproj, out);
}

// Round 10
// 190.342 us; speedup vs baseline: 1.0310x; 1.0310x over previous
//
#include <hip/hip_runtime.h>
#include <cstdint>
#include <cstddef>

namespace {

constexpr int kC = 512;
constexpr int kHW = 4096;            // H*W = 64*64
constexpr int kHeads = 8;
constexpr int kChunkElems = 64 * 64; // tokens per chunk * head dim

typedef float f32x4 __attribute__((ext_vector_type(4)));
typedef _Float16 f16x8 __attribute__((ext_vector_type(8)));
union FragU { uint4 u; f16x8 h; };

__device__ __forceinline__ ushort f16rn(float x) {
  _Float16 h = (_Float16)x;           // v_cvt_f16_f32, RNE
  ushort u;
  __builtin_memcpy(&u, &h, 2);
  return u;
}
__device__ __forceinline__ uint pack2(ushort a, ushort b) {
  return (uint)a | ((uint)b << 16);
}
__device__ __forceinline__ float fexp2(float x) {
  return exp2f(x);   // folds to v_exp_f32 under -O3 on gfx950
}
__device__ __forceinline__ uint pkrtz(float a, float b) {
  // v_cvt_pkrtz_f16_f32: two f32 -> packed f16x2, round-toward-zero.
  auto h = __builtin_amdgcn_cvt_pkrtz(a, b);
  uint u;
  __builtin_memcpy(&u, &h, 4);
  return u;
}
__device__ __forceinline__ void gld16(const void* g, void* lds) {
  __builtin_amdgcn_global_load_lds(
      (const __attribute__((address_space(1))) uint32_t*)g,
      (__attribute__((address_space(3))) uint32_t*)lds, 16, 0, 0);
}

// ---------------------------------------------------------------------------
// Kernel W16: single-plane f16 weight conversion, BOTH weights in one
// launch (512 blocks: 384 for wqkv 786432 elems, 128 for wproj 262144).
// ---------------------------------------------------------------------------
__global__ __launch_bounds__(256)
void convw16_kernel(const float* __restrict__ wqkv, ushort* __restrict__ wqh,
                    const float* __restrict__ wproj, ushort* __restrict__ wph)
{
  const int bx = blockIdx.x;
  const float* src;
  ushort* dst;
  int idx;
  if (bx < 384) { src = wqkv; dst = wqh; idx = (bx * 256 + threadIdx.x) * 8; }
  else { src = wproj; dst = wph; idx = ((bx - 384) * 256 + threadIdx.x) * 8; }
  float4 v0 = *(const float4*)(src + idx);
  float4 v1 = *(const float4*)(src + idx + 4);
  float xs[8] = {v0.x, v0.y, v0.z, v0.w, v1.x, v1.y, v1.z, v1.w};
  ushort hh[8];
#pragma unroll
  for (int e = 0; e < 8; ++e) hh[e] = f16rn(xs[e]);
  *(uint4*)(dst + idx) = make_uint4(pack2(hh[0], hh[1]), pack2(hh[2], hh[3]),
                                    pack2(hh[4], hh[5]), pack2(hh[6], hh[7]));
}

// ---------------------------------------------------------------------------
// Kernel 0: transpose + f16 x:  [b][c][t] fp32 -> xt [b][t][c] (f16 plane)
// ---------------------------------------------------------------------------
__global__ __launch_bounds__(256)
void convx_kernel(const float* __restrict__ x, ushort* __restrict__ xt)
{
  __shared__ float LT[64][68];
  const int tid = threadIdx.x;
  const int t0 = blockIdx.x * 64;
  const int c0 = blockIdx.y * 64;
  const int b  = blockIdx.z;
  const float* xb = x + (size_t)b * kC * kHW;

#pragma unroll
  for (int u = 0; u < 4; ++u) {
    int idx = tid + u * 256;
    int rc = idx >> 4;
    int t4 = (idx & 15) << 2;
    float4 val = *(const float4*)(xb + (size_t)(c0 + rc) * kHW + t0 + t4);
    LT[t4 + 0][rc] = val.x;
    LT[t4 + 1][rc] = val.y;
    LT[t4 + 2][rc] = val.z;
    LT[t4 + 3][rc] = val.w;
  }
  __syncthreads();
#pragma unroll
  for (int u = 0; u < 4; ++u) {
    int idx = tid + u * 256;
    int rt = idx >> 4;
    int c4 = (idx & 15) << 2;
    float4 v = *(const float4*)&LT[rt][c4];
    size_t o = ((size_t)b * kHW + t0 + rt) * kC + c0 + c4;
    *(ushort4*)(xt + o) = make_ushort4(f16rn(v.x), f16rn(v.y),
                                       f16rn(v.z), f16rn(v.w));
  }
}

// ---------------------------------------------------------------------------
// Kernel 1: QKV GEMM, single-plane f16 MFMA, DOUBLE-BUFFERED staging
// (r8 version — best measured 47.5us). 128x128 tile, BK=64, LDS 64KB.
// q scale folds log2e so attn softmax uses bare exp2.
// ---------------------------------------------------------------------------
__global__ __launch_bounds__(256)
void qkv_mfma_kernel(const ushort* __restrict__ xt,
                     const ushort* __restrict__ wq,
                     const float* __restrict__ bqkv,
                     ushort* __restrict__ qo, ushort* __restrict__ ko,
                     ushort* __restrict__ vo)
{
  __shared__ __align__(16) ushort As[2][128 * 64];   // x, 16KB each
  __shared__ __align__(16) ushort Bs[2][128 * 64];   // w, 16KB each

  const int tid  = threadIdx.x;
  const int lane = tid & 63;
  const int wv   = tid >> 6;
  const int quad = lane >> 4;
  const int l15  = lane & 15;
  const int wm = wv & 1, wn = wv >> 1;
  const int m0 = blockIdx.x * 128;   // t
  const int n0 = blockIdx.y * 128;   // j
  const int b  = blockIdx.z;

  const ushort* xb = xt + (size_t)b * kHW * kC;

  auto stage = [&](int buf, int k0) {
#pragma unroll
    for (int ii = 0; ii < 4; ++ii) {
      int i = wv * 4 + ii;                 // 16 x 1KB pieces per plane
      int m = i * 8 + (lane >> 3);         // tile-local row
      int gch = (lane & 7) ^ (m & 7);      // swizzled 16B chunk within row
      size_t goA = (size_t)(m0 + m) * kC + k0 + gch * 8;
      gld16(xb + goA, (char*)&As[buf][0] + i * 1024);
      size_t goB = (size_t)(n0 + m) * kC + k0 + gch * 8;
      gld16(wq + goB, (char*)&Bs[buf][0] + i * 1024);
    }
  };

  f32x4 acc[4][4];
#pragma unroll
  for (int i = 0; i < 4; ++i)
#pragma unroll
    for (int j = 0; j < 4; ++j) acc[i][j] = (f32x4){0.f, 0.f, 0.f, 0.f};

  stage(0, 0);
  asm volatile("s_waitcnt vmcnt(0)" ::: "memory");
  asm volatile("s_barrier" ::: "memory");

  for (int kt = 0; kt < 8; ++kt) {
    const int cur = kt & 1;
    if (kt < 7) stage(cur ^ 1, (kt + 1) * 64);

    const ushort* Ac = &As[cur][0];
    const ushort* Bc = &Bs[cur][0];
#pragma unroll
    for (int s = 0; s < 2; ++s) {
      const int gq = s * 4 + quad;         // global 16B chunk index (k)
      FragU aA[4], bB[4];
#pragma unroll
      for (int mi = 0; mi < 4; ++mi) {
        int mr = wm * 64 + mi * 16 + l15;
        int off = mr * 64 + ((gq ^ (mr & 7)) * 8);
        aA[mi].u = *(const uint4*)&Ac[off];
      }
#pragma unroll
      for (int ni = 0; ni < 4; ++ni) {
        int nr = wn * 64 + ni * 16 + l15;
        int off = nr * 64 + ((gq ^ (nr & 7)) * 8);
        bB[ni].u = *(const uint4*)&Bc[off];
      }
#pragma unroll
      for (int mi = 0; mi < 4; ++mi)
#pragma unroll
        for (int ni = 0; ni < 4; ++ni)
          acc[mi][ni] = __builtin_amdgcn_mfma_f32_16x16x32_f16(aA[mi].h, bB[ni].h, acc[mi][ni], 0, 0, 0);
    }

    asm volatile("s_waitcnt lgkmcnt(0)" ::: "memory");  // my ds_reads drained
    if (kt < 7) asm volatile("s_waitcnt vmcnt(0)" ::: "memory");  // next buf in
    asm volatile("s_barrier" ::: "memory");
  }

  // ---- epilogue ----
  const int sec = n0 >> 9;                 // block-uniform: 0=q,1=k,2=v
  const int jwbase = n0 + wn * 64;         // 64-aligned -> head fixed per wave
  const int head = (jwbase >> 6) & 7;
  const size_t hbb = ((size_t)b * kHeads + head) * 64;
  float biasv[4];
#pragma unroll
  for (int ni = 0; ni < 4; ++ni) biasv[ni] = bqkv[jwbase + ni * 16 + l15];

  if (sec == 2) {
    // v: transposed [dd][tok]; lane's 4 acc rows are 4 consecutive toks
#pragma unroll
    for (int ni = 0; ni < 4; ++ni) {
      int dd = ni * 16 + l15;
#pragma unroll
      for (int mi = 0; mi < 4; ++mi) {
        int t0t = m0 + wm * 64 + mi * 16 + quad * 4;
        int h = t0t >> 6, w = t0t & 63;
        int cy = h >> 3, iy = h & 7, cx = w >> 3, ix = w & 7;
        size_t cb = (hbb + cy * 8 + cx) * (size_t)kChunkElems;
        int tokb = iy * 8 + ix;
        ushort hh[4];
#pragma unroll
        for (int r = 0; r < 4; ++r) hh[r] = f16rn(acc[mi][ni][r] + biasv[ni]);
        *(ushort4*)(vo + cb + (size_t)dd * 64 + tokb) = make_ushort4(hh[0], hh[1], hh[2], hh[3]);
      }
    }
  } else {
    // q/k: per-wave-private LDS transpose -> vectorized uint4 stores.
    // (scratch lives in As[0]; loop's final barrier freed all LDS)
    ushort* dst = (sec == 0) ? qo : ko;
    // q pre-scaled by 1/8 (d^-1/2) AND log2e so attn uses exp2 directly.
    const float sc = (sec == 0) ? 0.125f * 1.44269504089f : 1.0f;
    ushort* tH = &As[0][0] + wv * 1152;
    const int ltok = lane >> 2;
    const int dd0 = (lane & 3) * 16;
#pragma unroll
    for (int mi = 0; mi < 4; ++mi) {
#pragma unroll
      for (int ni = 0; ni < 4; ++ni)
#pragma unroll
        for (int r = 0; r < 4; ++r)
          tH[(quad * 4 + r) * 68 + ni * 16 + l15] =
              f16rn((acc[mi][ni][r] + biasv[ni]) * sc);
      int tg = m0 + wm * 64 + mi * 16 + ltok;
      int h = tg >> 6, w = tg & 63;
      int cy = h >> 3, iy = h & 7, cx = w >> 3, ix = w & 7;
      size_t cb = (hbb + cy * 8 + cx) * (size_t)kChunkElems
                + (size_t)(iy * 8 + ix) * 64 + dd0;
      uint4 h0 = *(const uint4*)&tH[ltok * 68 + dd0];
      uint4 h1 = *(const uint4*)&tH[ltok * 68 + dd0 + 8];
      *(uint4*)(dst + cb) = h0;
      *(uint4*)(dst + cb + 8) = h1;
    }
  }
}

// ---------------------------------------------------------------------------
// Kernel 2: MFMA flash attention (swapped-operand, split-staged schedule,
// VALU-minimized, single f16 ao plane). Unchanged from r8.
// ---------------------------------------------------------------------------
__global__ __launch_bounds__(256)
void attn_mfma_kernel(const ushort* __restrict__ qg, const ushort* __restrict__ kg,
                      const ushort* __restrict__ vg,
                      ushort* __restrict__ ao)
{
  __shared__ __align__(16) ushort KB[4096], VB[4096];  // 8KB each
  __shared__ __align__(16) ushort Ps[4 * 16 * 72];     // per-wave 16x72

  const int tid  = threadIdx.x;
  const int lane = tid & 63;
  const int wv   = tid >> 6;
  const int quad = lane >> 4;
  const int l15  = lane & 15;

  // XCD-aware swizzle: group g (b,head) pinned to XCD bx&7 (4 groups/XCD).
  const int bx = blockIdx.x;
  const int g  = (bx & 7) * 4 + ((bx >> 3) >> 6);  // 0..31
  const int c  = (bx >> 3) & 63;                   // chunk in group
  const int b = g >> 3, head = g & 7;
  const int cy = c >> 3, cx = c & 7;

  const size_t hb = (size_t)b * kHeads + head;
  const size_t gbase = hb * 64 * (size_t)kChunkElems;   // group base
  const size_t cbase = gbase + (size_t)c * (size_t)kChunkElems;

  FragU aQ0, aQ1;
  {
    const ushort* qr = qg + cbase + (size_t)(wv * 16 + l15) * 64 + quad * 8;
    aQ0.u = *(const uint4*)(qr);
    aQ1.u = *(const uint4*)(qr + 32);
  }

  // per-lane staging bases (include boff + wave piece offset)
  const int boff = ((lane >> 3) * 64) + (((lane & 7) ^ (lane >> 3)) * 8);
  const ushort* kgB = kg + gbase + boff + (size_t)(wv * 2) * 512;
  const ushort* vgB = vg + gbase + boff + (size_t)(wv * 2) * 512;
  char* kDst0 = (char*)KB + (wv * 2) * 1024;
  char* vDst0 = (char*)VB + (wv * 2) * 1024;

  // hoisted K/V LDS fragment offsets (loop-invariant)
  int kvOff0[4], kvOff1[4];
  {
    const int sw = l15 & 7;
#pragma unroll
    for (int nt = 0; nt < 4; ++nt) {
      int row = nt * 16 + l15;
      kvOff0[nt] = row * 64 + ((quad ^ sw) * 8);
      kvOff1[nt] = row * 64 + (((4 + quad) ^ sw) * 8);
    }
  }

  ushort* PsW = Ps + wv * 1152;          // per-wave 16 x 72
  ushort* pWr = PsW + l15 * 72 + quad * 4;
  const ushort* pRd = PsW + l15 * 72 + quad * 8;

  // packed valid-neighbor chunk list (block-uniform -> SALU)
  unsigned long long list = 0ull;
  int cnt = 0;
#pragma unroll
  for (int p = 0; p < 9; ++p) {
    const int dy = p / 3 - 1, dx = p % 3 - 1;   // compile-time constants
    int ny = cy + dy, nx = cx + dx;
    if ((unsigned)ny < 8u && (unsigned)nx < 8u) {
      list |= (unsigned long long)(ny * 8 + nx) << (6 * cnt);
      ++cnt;
    }
  }

  f32x4 o[4];
#pragma unroll
  for (int r = 0; r < 4; ++r) o[r] = (f32x4){0.f, 0.f, 0.f, 0.f};
  float rsum = 0.f;

  {
    int ch0 = (int)(list & 63);
    const ushort* pk = kgB + (size_t)ch0 * kChunkElems;
    gld16(pk, kDst0);
    gld16(pk + 512, kDst0 + 1024);
    const ushort* pv = vgB + (size_t)ch0 * kChunkElems;
    gld16(pv, vDst0);
    gld16(pv + 512, vDst0 + 1024);
  }

  for (int i = 0; i < cnt; ++i) {
    const bool more = (i + 1 < cnt);
    const int chn = (int)((list >> (6 * (i + 1))) & 63);  // unused if !more

    // top: own K(i) landed (V(i) may still be in flight)
    asm volatile("s_waitcnt vmcnt(2)" ::: "memory");
    asm volatile("s_barrier" ::: "memory");   // KB valid for all waves

    FragU kf[8];
#pragma unroll
    for (int nt = 0; nt < 4; ++nt) {
      kf[nt * 2].u     = *(const uint4*)&KB[kvOff0[nt]];
      kf[nt * 2 + 1].u = *(const uint4*)&KB[kvOff1[nt]];
    }
    asm volatile("s_waitcnt lgkmcnt(0)" ::: "memory");  // K frags in regs
    asm volatile("s_waitcnt vmcnt(0)" ::: "memory");    // own V(i) landed
    asm volatile("s_barrier" ::: "memory");   // KB free, VB valid for all

    if (more) {
      const ushort* pk = kgB + (size_t)chn * kChunkElems;
      gld16(pk, kDst0);
      gld16(pk + 512, kDst0 + 1024);
    }

    // S^T = K * Q^T : lane -> S[key = nt*16 + quad*4 + r][q = l15]
    f32x4 s[4];
#pragma unroll
    for (int nt = 0; nt < 4; ++nt) s[nt] = (f32x4){0.f, 0.f, 0.f, 0.f};
#pragma unroll
    for (int nt = 0; nt < 4; ++nt) {
      s[nt] = __builtin_amdgcn_mfma_f32_16x16x32_f16(kf[nt * 2].h, aQ0.h, s[nt], 0, 0, 0);
      s[nt] = __builtin_amdgcn_mfma_f32_16x16x32_f16(kf[nt * 2 + 1].h, aQ1.h, s[nt], 0, 0, 0);
    }

    // P = exp2(S') (log2e pre-folded into q); pack via cvt_pkrtz; b64 store
#pragma unroll
    for (int nt = 0; nt < 4; ++nt) {
      float e0 = fexp2(s[nt][0]);
      float e1 = fexp2(s[nt][1]);
      float e2 = fexp2(s[nt][2]);
      float e3 = fexp2(s[nt][3]);
      rsum += (e0 + e1) + (e2 + e3);
      *(uint2*)(pWr + nt * 16) = make_uint2(pkrtz(e0, e1), pkrtz(e2, e3));
    }

    FragU aP0, aP1;
    aP0.u = *(const uint4*)(pRd);
    aP1.u = *(const uint4*)(pRd + 32);

    // O^T = V^T * P^T : lane -> O[q = l15][dd = nt*16 + quad*4 + r]
#pragma unroll
    for (int nt = 0; nt < 4; ++nt) {
      FragU v0, v1;
      v0.u = *(const uint4*)&VB[kvOff0[nt]];
      v1.u = *(const uint4*)&VB[kvOff1[nt]];
      o[nt] = __builtin_amdgcn_mfma_f32_16x16x32_f16(v0.h, aP0.h, o[nt], 0, 0, 0);
      o[nt] = __builtin_amdgcn_mfma_f32_16x16x32_f16(v1.h, aP1.h, o[nt], 0, 0, 0);
    }

    asm volatile("s_waitcnt lgkmcnt(0)" ::: "memory");  // V reads drained
    asm volatile("s_barrier" ::: "memory");   // VB free
    if (more) {
      const ushort* pv = vgB + (size_t)chn * kChunkElems;
      gld16(pv, vDst0);
      gld16(pv + 512, vDst0 + 1024);
    }
  }

  // ---- row-sum reduce across the 4 quad partners (q = l15 fixed per lane)
  rsum += __shfl_xor(rsum, 16, 64);
  rsum += __shfl_xor(rsum, 32, 64);
  const float inv = 1.0f / rsum;

  // ---- epilogue: lane holds one token's row (q = wv*16 + l15); store ao
  // as a single f16 plane straight from registers, 8B per nt.
  const int trg = wv * 16 + l15;
  const int hp = cy * 8 + (trg >> 3);
  const int wp = cx * 8 + (trg & 7);
  const size_t obase = ((size_t)b * kHW + hp * 64 + wp) * (size_t)kC + head * 64;

#pragma unroll
  for (int nt = 0; nt < 4; ++nt) {
    float v0 = o[nt][0] * inv;
    float v1 = o[nt][1] * inv;
    float v2 = o[nt][2] * inv;
    float v3 = o[nt][3] * inv;
    *(ushort4*)(ao + obase + nt * 16 + quad * 4) =
        make_ushort4(f16rn(v0), f16rn(v1), f16rn(v2), f16rn(v3));
  }
}

// ---------------------------------------------------------------------------
// Kernel 3: output projection, single-plane f16 MFMA, 128x128 tile,
// double-buffered (same loop structure as qkv — acc[4][4], 64KB LDS).
// Halves per-output barrier overhead + wproj panel re-reads vs 128x64.
// ---------------------------------------------------------------------------
__global__ __launch_bounds__(256)
void proj_mfma_kernel(const ushort* __restrict__ ao,
                      const ushort* __restrict__ wp,
                      const float* __restrict__ bproj,
                      float* __restrict__ out)
{
  __shared__ __align__(16) ushort As[2][128 * 64];   // wproj 16KB each
  __shared__ __align__(16) ushort Bs[2][128 * 64];   // ao 16KB each

  const int tid  = threadIdx.x;
  const int lane = tid & 63;
  const int wv   = tid >> 6;
  const int quad = lane >> 4;
  const int l15  = lane & 15;
  const int wm = wv & 1, wn = wv >> 1;
  const int n0g = blockIdx.x * 128;   // global t (batch-fused, 0..16383)
  const int m0  = blockIdx.y * 128;   // c
  const int b   = n0g >> 12;
  const int tl0 = n0g & 4095;

  auto stage = [&](int buf, int k0) {
#pragma unroll
    for (int ii = 0; ii < 4; ++ii) {
      int i = wv * 4 + ii;
      int m = i * 8 + (lane >> 3);
      int gch = (lane & 7) ^ (m & 7);
      size_t goA = (size_t)(m0 + m) * kC + k0 + gch * 8;
      gld16(wp + goA, (char*)&As[buf][0] + i * 1024);
      size_t goB = (size_t)(n0g + m) * kC + k0 + gch * 8;
      gld16(ao + goB, (char*)&Bs[buf][0] + i * 1024);
    }
  };

  f32x4 acc[4][4];
#pragma unroll
  for (int i = 0; i < 4; ++i)
#pragma unroll
    for (int j = 0; j < 4; ++j) acc[i][j] = (f32x4){0.f, 0.f, 0.f, 0.f};

  stage(0, 0);
  asm volatile("s_waitcnt vmcnt(0)" ::: "memory");
  asm volatile("s_barrier" ::: "memory");

  for (int kt = 0; kt < 8; ++kt) {
    const int cur = kt & 1;
    if (kt < 7) stage(cur ^ 1, (kt + 1) * 64);

    const ushort* Ac = &As[cur][0];
    const ushort* Bc = &Bs[cur][0];
#pragma unroll
    for (int s = 0; s < 2; ++s) {
      const int gq = s * 4 + quad;
      FragU aA[4], bB[4];
#pragma unroll
      for (int mi = 0; mi < 4; ++mi) {
        int mr = wm * 64 + mi * 16 + l15;
        int off = mr * 64 + ((gq ^ (mr & 7)) * 8);
        aA[mi].u = *(const uint4*)&Ac[off];
      }
#pragma unroll
      for (int ni = 0; ni < 4; ++ni) {
        int nr = wn * 64 + ni * 16 + l15;
        int off = nr * 64 + ((gq ^ (nr & 7)) * 8);
        bB[ni].u = *(const uint4*)&Bc[off];
      }
#pragma unroll
      for (int mi = 0; mi < 4; ++mi)
#pragma unroll
        for (int ni = 0; ni < 4; ++ni)
          acc[mi][ni] = __builtin_amdgcn_mfma_f32_16x16x32_f16(aA[mi].h, bB[ni].h, acc[mi][ni], 0, 0, 0);
    }

    asm volatile("s_waitcnt lgkmcnt(0)" ::: "memory");
    if (kt < 7) asm volatile("s_waitcnt vmcnt(0)" ::: "memory");
    asm volatile("s_barrier" ::: "memory");
  }

#pragma unroll
  for (int mi = 0; mi < 4; ++mi)
#pragma unroll
    for (int r = 0; r < 4; ++r) {
      int c = m0 + wm * 64 + mi * 16 + quad * 4 + r;
      float bias = bproj[c];
      size_t rowb = ((size_t)b * kC + c) * (size_t)kHW + tl0 + wn * 64;
#pragma unroll
      for (int ni = 0; ni < 4; ++ni)
        out[rowb + ni * 16 + l15] = acc[mi][ni][r] + bias;
    }
}

}  // namespace

extern "C" void kernel_launch(void* const* d_in, const int* in_sizes, int n_in,
                              void* d_out, int out_size, void* d_ws, size_t ws_size,
                              hipStream_t stream)
{
  const float* x     = (const float*)d_in[0];
  const float* wqkv  = (const float*)d_in[1];
  const float* bqkv  = (const float*)d_in[2];
  const float* wproj = (const float*)d_in[3];
  const float* bproj = (const float*)d_in[4];
  float* out = (float*)d_out;

  const size_t seg = (size_t)2048 * kChunkElems;  // 8,388,608 elems
  ushort* base = (ushort*)d_ws;
  ushort* qb = base + 0 * seg;
  ushort* kb = base + 1 * seg;
  ushort* vb = base + 2 * seg;
  ushort* xt = base + 3 * seg;
  ushort* ao = xt;                       // alias (xt dead after qkv GEMM)
  ushort* wp16 = base + 4 * seg;         // free slot (old ao_lo, dead since r7)
  ushort* wqh = base + 5 * seg;          // 1536*512 = 786432 elems (f16)

  convw16_kernel<<<dim3(512), 256, 0, stream>>>(wqkv, wqh, wproj, wp16);
  convx_kernel<<<dim3(64, 8, 4), 256, 0, stream>>>(x, xt);
  qkv_mfma_kernel<<<dim3(32, 12, 4), 256, 0, stream>>>(xt, wqh, bqkv,
                                                       qb, kb, vb);
  attn_mfma_kernel<<<dim3(2048), 256, 0, stream>>>(qb, kb, vb, ao);
  proj_mfma_kernel<<<dim3(128, 4), 256, 0, stream>>>(ao, wp16, bproj, out);
}

// Round 11
// 176.917 us; speedup vs baseline: 1.1092x; 1.0759x over previous
//
#include <hip/hip_runtime.h>
#include <cstdint>
#include <cstddef>

namespace {

constexpr int kC = 512;
constexpr int kHW = 4096;            // H*W = 64*64
constexpr int kHeads = 8;
constexpr int kChunkElems = 64 * 64; // tokens per chunk * head dim

typedef float f32x4 __attribute__((ext_vector_type(4)));
typedef _Float16 f16x8 __attribute__((ext_vector_type(8)));
union FragU { uint4 u; f16x8 h; };

__device__ __forceinline__ ushort f16rn(float x) {
  _Float16 h = (_Float16)x;           // v_cvt_f16_f32, RNE
  ushort u;
  __builtin_memcpy(&u, &h, 2);
  return u;
}
__device__ __forceinline__ uint pack2(ushort a, ushort b) {
  return (uint)a | ((uint)b << 16);
}
__device__ __forceinline__ float fexp2(float x) {
  return exp2f(x);   // folds to v_exp_f32 under -O3 on gfx950
}
__device__ __forceinline__ uint pkrtz(float a, float b) {
  // v_cvt_pkrtz_f16_f32: two f32 -> packed f16x2, round-toward-zero.
  auto h = __builtin_amdgcn_cvt_pkrtz(a, b);
  uint u;
  __builtin_memcpy(&u, &h, 4);
  return u;
}
__device__ __forceinline__ void gld16(const void* g, void* lds) {
  __builtin_amdgcn_global_load_lds(
      (const __attribute__((address_space(1))) uint32_t*)g,
      (__attribute__((address_space(3))) uint32_t*)lds, 16, 0, 0);
}

// ---------------------------------------------------------------------------
// Kernel W16: single-plane f16 weight conversion, BOTH weights in one
// launch (512 blocks: 384 for wqkv 786432 elems, 128 for wproj 262144).
// ---------------------------------------------------------------------------
__global__ __launch_bounds__(256)
void convw16_kernel(const float* __restrict__ wqkv, ushort* __restrict__ wqh,
                    const float* __restrict__ wproj, ushort* __restrict__ wph)
{
  const int bx = blockIdx.x;
  const float* src;
  ushort* dst;
  int idx;
  if (bx < 384) { src = wqkv; dst = wqh; idx = (bx * 256 + threadIdx.x) * 8; }
  else { src = wproj; dst = wph; idx = ((bx - 384) * 256 + threadIdx.x) * 8; }
  float4 v0 = *(const float4*)(src + idx);
  float4 v1 = *(const float4*)(src + idx + 4);
  float xs[8] = {v0.x, v0.y, v0.z, v0.w, v1.x, v1.y, v1.z, v1.w};
  ushort hh[8];
#pragma unroll
  for (int e = 0; e < 8; ++e) hh[e] = f16rn(xs[e]);
  *(uint4*)(dst + idx) = make_uint4(pack2(hh[0], hh[1]), pack2(hh[2], hh[3]),
                                    pack2(hh[4], hh[5]), pack2(hh[6], hh[7]));
}

// ---------------------------------------------------------------------------
// Kernel 0: transpose + f16 x:  [b][c][t] fp32 -> xt [b][t][c] (f16 plane)
// ---------------------------------------------------------------------------
__global__ __launch_bounds__(256)
void convx_kernel(const float* __restrict__ x, ushort* __restrict__ xt)
{
  __shared__ float LT[64][68];
  const int tid = threadIdx.x;
  const int t0 = blockIdx.x * 64;
  const int c0 = blockIdx.y * 64;
  const int b  = blockIdx.z;
  const float* xb = x + (size_t)b * kC * kHW;

#pragma unroll
  for (int u = 0; u < 4; ++u) {
    int idx = tid + u * 256;
    int rc = idx >> 4;
    int t4 = (idx & 15) << 2;
    float4 val = *(const float4*)(xb + (size_t)(c0 + rc) * kHW + t0 + t4);
    LT[t4 + 0][rc] = val.x;
    LT[t4 + 1][rc] = val.y;
    LT[t4 + 2][rc] = val.z;
    LT[t4 + 3][rc] = val.w;
  }
  __syncthreads();
#pragma unroll
  for (int u = 0; u < 4; ++u) {
    int idx = tid + u * 256;
    int rt = idx >> 4;
    int c4 = (idx & 15) << 2;
    float4 v = *(const float4*)&LT[rt][c4];
    size_t o = ((size_t)b * kHW + t0 + rt) * kC + c0 + c4;
    *(ushort4*)(xt + o) = make_ushort4(f16rn(v.x), f16rn(v.y),
                                       f16rn(v.z), f16rn(v.w));
  }
}

// ---------------------------------------------------------------------------
// Kernel 1: QKV GEMM, single-plane f16 MFMA. SINGLE-BUFFER + REGISTER
// PRELOAD staging (attn-r4 proven pattern): per K-step
//   vmcnt(0); bar        -> LDS tile kt valid for all waves
//   16x ds_read_b128 (ALL fragments) -> regs; lgkmcnt(0); bar -> LDS free
//   stage(kt+1)          (latency hidden under the 32 MFMAs)
//   32 MFMA on registers
// LDS 32KB + VGPR ~150 -> 3 blocks/CU (37.5% occ cap) with dbuf-grade
// hiding: +50% TLP over r8's 64KB dbuf (2 blocks/CU).
// q scale folds log2e so attn softmax uses bare exp2.
// ---------------------------------------------------------------------------
__global__ __launch_bounds__(256)
void qkv_mfma_kernel(const ushort* __restrict__ xt,
                     const ushort* __restrict__ wq,
                     const float* __restrict__ bqkv,
                     ushort* __restrict__ qo, ushort* __restrict__ ko,
                     ushort* __restrict__ vo)
{
  __shared__ __align__(16) ushort As[128 * 64];   // x, 16KB
  __shared__ __align__(16) ushort Bs[128 * 64];   // w, 16KB

  const int tid  = threadIdx.x;
  const int lane = tid & 63;
  const int wv   = tid >> 6;
  const int quad = lane >> 4;
  const int l15  = lane & 15;
  const int wm = wv & 1, wn = wv >> 1;
  const int m0 = blockIdx.x * 128;   // t
  const int n0 = blockIdx.y * 128;   // j
  const int b  = blockIdx.z;

  const ushort* xb = xt + (size_t)b * kHW * kC;

  auto stage = [&](int k0) {
#pragma unroll
    for (int ii = 0; ii < 4; ++ii) {
      int i = wv * 4 + ii;                 // 16 x 1KB pieces per plane
      int m = i * 8 + (lane >> 3);         // tile-local row
      int gch = (lane & 7) ^ (m & 7);      // swizzled 16B chunk within row
      gld16(xb + (size_t)(m0 + m) * kC + k0 + gch * 8, (char*)As + i * 1024);
      gld16(wq + (size_t)(n0 + m) * kC + k0 + gch * 8, (char*)Bs + i * 1024);
    }
  };

  f32x4 acc[4][4];
#pragma unroll
  for (int i = 0; i < 4; ++i)
#pragma unroll
    for (int j = 0; j < 4; ++j) acc[i][j] = (f32x4){0.f, 0.f, 0.f, 0.f};

  stage(0);

  for (int kt = 0; kt < 8; ++kt) {
    asm volatile("s_waitcnt vmcnt(0)" ::: "memory");   // own stage landed
    asm volatile("s_barrier" ::: "memory");            // tile valid for all

    FragU a0[4], a1[4], b0[4], b1[4];
#pragma unroll
    for (int mi = 0; mi < 4; ++mi) {
      int mr = wm * 64 + mi * 16 + l15;
      int sw = mr & 7;
      a0[mi].u = *(const uint4*)&As[mr * 64 + ((quad ^ sw) * 8)];
      a1[mi].u = *(const uint4*)&As[mr * 64 + (((4 + quad) ^ sw) * 8)];
    }
#pragma unroll
    for (int ni = 0; ni < 4; ++ni) {
      int nr = wn * 64 + ni * 16 + l15;
      int sw = nr & 7;
      b0[ni].u = *(const uint4*)&Bs[nr * 64 + ((quad ^ sw) * 8)];
      b1[ni].u = *(const uint4*)&Bs[nr * 64 + (((4 + quad) ^ sw) * 8)];
    }
    asm volatile("s_waitcnt lgkmcnt(0)" ::: "memory"); // frags in regs
    asm volatile("s_barrier" ::: "memory");            // LDS free to restage

    if (kt < 7) stage((kt + 1) * 64);                  // hidden under MFMAs

#pragma unroll
    for (int mi = 0; mi < 4; ++mi)
#pragma unroll
      for (int ni = 0; ni < 4; ++ni)
        acc[mi][ni] = __builtin_amdgcn_mfma_f32_16x16x32_f16(a0[mi].h, b0[ni].h, acc[mi][ni], 0, 0, 0);
#pragma unroll
    for (int mi = 0; mi < 4; ++mi)
#pragma unroll
      for (int ni = 0; ni < 4; ++ni)
        acc[mi][ni] = __builtin_amdgcn_mfma_f32_16x16x32_f16(a1[mi].h, b1[ni].h, acc[mi][ni], 0, 0, 0);
  }

  // ---- epilogue ----  (all LDS free; As reused as per-wave scratch)
  const int sec = n0 >> 9;                 // block-uniform: 0=q,1=k,2=v
  const int jwbase = n0 + wn * 64;         // 64-aligned -> head fixed per wave
  const int head = (jwbase >> 6) & 7;
  const size_t hbb = ((size_t)b * kHeads + head) * 64;
  float biasv[4];
#pragma unroll
  for (int ni = 0; ni < 4; ++ni) biasv[ni] = bqkv[jwbase + ni * 16 + l15];

  if (sec == 2) {
    // v: transposed [dd][tok]; lane's 4 acc rows are 4 consecutive toks
#pragma unroll
    for (int ni = 0; ni < 4; ++ni) {
      int dd = ni * 16 + l15;
#pragma unroll
      for (int mi = 0; mi < 4; ++mi) {
        int t0t = m0 + wm * 64 + mi * 16 + quad * 4;
        int h = t0t >> 6, w = t0t & 63;
        int cy = h >> 3, iy = h & 7, cx = w >> 3, ix = w & 7;
        size_t cb = (hbb + cy * 8 + cx) * (size_t)kChunkElems;
        int tokb = iy * 8 + ix;
        ushort hh[4];
#pragma unroll
        for (int r = 0; r < 4; ++r) hh[r] = f16rn(acc[mi][ni][r] + biasv[ni]);
        *(ushort4*)(vo + cb + (size_t)dd * 64 + tokb) = make_ushort4(hh[0], hh[1], hh[2], hh[3]);
      }
    }
  } else {
    // q/k: per-wave-private LDS transpose -> vectorized uint4 stores.
    ushort* dst = (sec == 0) ? qo : ko;
    // q pre-scaled by 1/8 (d^-1/2) AND log2e so attn uses exp2 directly.
    const float sc = (sec == 0) ? 0.125f * 1.44269504089f : 1.0f;
    ushort* tH = As + wv * 1152;
    const int ltok = lane >> 2;
    const int dd0 = (lane & 3) * 16;
#pragma unroll
    for (int mi = 0; mi < 4; ++mi) {
#pragma unroll
      for (int ni = 0; ni < 4; ++ni)
#pragma unroll
        for (int r = 0; r < 4; ++r)
          tH[(quad * 4 + r) * 68 + ni * 16 + l15] =
              f16rn((acc[mi][ni][r] + biasv[ni]) * sc);
      int tg = m0 + wm * 64 + mi * 16 + ltok;
      int h = tg >> 6, w = tg & 63;
      int cy = h >> 3, iy = h & 7, cx = w >> 3, ix = w & 7;
      size_t cb = (hbb + cy * 8 + cx) * (size_t)kChunkElems
                + (size_t)(iy * 8 + ix) * 64 + dd0;
      uint4 h0 = *(const uint4*)&tH[ltok * 68 + dd0];
      uint4 h1 = *(const uint4*)&tH[ltok * 68 + dd0 + 8];
      *(uint4*)(dst + cb) = h0;
      *(uint4*)(dst + cb + 8) = h1;
    }
  }
}

// ---------------------------------------------------------------------------
// Kernel 2: MFMA flash attention (swapped-operand, split-staged schedule,
// VALU-minimized, single f16 ao plane). Unchanged from r10.
// ---------------------------------------------------------------------------
__global__ __launch_bounds__(256)
void attn_mfma_kernel(const ushort* __restrict__ qg, const ushort* __restrict__ kg,
                      const ushort* __restrict__ vg,
                      ushort* __restrict__ ao)
{
  __shared__ __align__(16) ushort KB[4096], VB[4096];  // 8KB each
  __shared__ __align__(16) ushort Ps[4 * 16 * 72];     // per-wave 16x72

  const int tid  = threadIdx.x;
  const int lane = tid & 63;
  const int wv   = tid >> 6;
  const int quad = lane >> 4;
  const int l15  = lane & 15;

  // XCD-aware swizzle: group g (b,head) pinned to XCD bx&7 (4 groups/XCD).
  const int bx = blockIdx.x;
  const int g  = (bx & 7) * 4 + ((bx >> 3) >> 6);  // 0..31
  const int c  = (bx >> 3) & 63;                   // chunk in group
  const int b = g >> 3, head = g & 7;
  const int cy = c >> 3, cx = c & 7;

  const size_t hb = (size_t)b * kHeads + head;
  const size_t gbase = hb * 64 * (size_t)kChunkElems;   // group base
  const size_t cbase = gbase + (size_t)c * (size_t)kChunkElems;

  FragU aQ0, aQ1;
  {
    const ushort* qr = qg + cbase + (size_t)(wv * 16 + l15) * 64 + quad * 8;
    aQ0.u = *(const uint4*)(qr);
    aQ1.u = *(const uint4*)(qr + 32);
  }

  // per-lane staging bases (include boff + wave piece offset)
  const int boff = ((lane >> 3) * 64) + (((lane & 7) ^ (lane >> 3)) * 8);
  const ushort* kgB = kg + gbase + boff + (size_t)(wv * 2) * 512;
  const ushort* vgB = vg + gbase + boff + (size_t)(wv * 2) * 512;
  char* kDst0 = (char*)KB + (wv * 2) * 1024;
  char* vDst0 = (char*)VB + (wv * 2) * 1024;

  // hoisted K/V LDS fragment offsets (loop-invariant)
  int kvOff0[4], kvOff1[4];
  {
    const int sw = l15 & 7;
#pragma unroll
    for (int nt = 0; nt < 4; ++nt) {
      int row = nt * 16 + l15;
      kvOff0[nt] = row * 64 + ((quad ^ sw) * 8);
      kvOff1[nt] = row * 64 + (((4 + quad) ^ sw) * 8);
    }
  }

  ushort* PsW = Ps + wv * 1152;          // per-wave 16 x 72
  ushort* pWr = PsW + l15 * 72 + quad * 4;
  const ushort* pRd = PsW + l15 * 72 + quad * 8;

  // packed valid-neighbor chunk list (block-uniform -> SALU)
  unsigned long long list = 0ull;
  int cnt = 0;
#pragma unroll
  for (int p = 0; p < 9; ++p) {
    const int dy = p / 3 - 1, dx = p % 3 - 1;   // compile-time constants
    int ny = cy + dy, nx = cx + dx;
    if ((unsigned)ny < 8u && (unsigned)nx < 8u) {
      list |= (unsigned long long)(ny * 8 + nx) << (6 * cnt);
      ++cnt;
    }
  }

  f32x4 o[4];
#pragma unroll
  for (int r = 0; r < 4; ++r) o[r] = (f32x4){0.f, 0.f, 0.f, 0.f};
  float rsum = 0.f;

  {
    int ch0 = (int)(list & 63);
    const ushort* pk = kgB + (size_t)ch0 * kChunkElems;
    gld16(pk, kDst0);
    gld16(pk + 512, kDst0 + 1024);
    const ushort* pv = vgB + (size_t)ch0 * kChunkElems;
    gld16(pv, vDst0);
    gld16(pv + 512, vDst0 + 1024);
  }

  for (int i = 0; i < cnt; ++i) {
    const bool more = (i + 1 < cnt);
    const int chn = (int)((list >> (6 * (i + 1))) & 63);  // unused if !more

    // top: own K(i) landed (V(i) may still be in flight)
    asm volatile("s_waitcnt vmcnt(2)" ::: "memory");
    asm volatile("s_barrier" ::: "memory");   // KB valid for all waves

    FragU kf[8];
#pragma unroll
    for (int nt = 0; nt < 4; ++nt) {
      kf[nt * 2].u     = *(const uint4*)&KB[kvOff0[nt]];
      kf[nt * 2 + 1].u = *(const uint4*)&KB[kvOff1[nt]];
    }
    asm volatile("s_waitcnt lgkmcnt(0)" ::: "memory");  // K frags in regs
    asm volatile("s_waitcnt vmcnt(0)" ::: "memory");    // own V(i) landed
    asm volatile("s_barrier" ::: "memory");   // KB free, VB valid for all

    if (more) {
      const ushort* pk = kgB + (size_t)chn * kChunkElems;
      gld16(pk, kDst0);
      gld16(pk + 512, kDst0 + 1024);
    }

    // S^T = K * Q^T : lane -> S[key = nt*16 + quad*4 + r][q = l15]
    f32x4 s[4];
#pragma unroll
    for (int nt = 0; nt < 4; ++nt) s[nt] = (f32x4){0.f, 0.f, 0.f, 0.f};
#pragma unroll
    for (int nt = 0; nt < 4; ++nt) {
      s[nt] = __builtin_amdgcn_mfma_f32_16x16x32_f16(kf[nt * 2].h, aQ0.h, s[nt], 0, 0, 0);
      s[nt] = __builtin_amdgcn_mfma_f32_16x16x32_f16(kf[nt * 2 + 1].h, aQ1.h, s[nt], 0, 0, 0);
    }

    // P = exp2(S') (log2e pre-folded into q); pack via cvt_pkrtz; b64 store
#pragma unroll
    for (int nt = 0; nt < 4; ++nt) {
      float e0 = fexp2(s[nt][0]);
      float e1 = fexp2(s[nt][1]);
      float e2 = fexp2(s[nt][2]);
      float e3 = fexp2(s[nt][3]);
      rsum += (e0 + e1) + (e2 + e3);
      *(uint2*)(pWr + nt * 16) = make_uint2(pkrtz(e0, e1), pkrtz(e2, e3));
    }

    FragU aP0, aP1;
    aP0.u = *(const uint4*)(pRd);
    aP1.u = *(const uint4*)(pRd + 32);

    // O^T = V^T * P^T : lane -> O[q = l15][dd = nt*16 + quad*4 + r]
#pragma unroll
    for (int nt = 0; nt < 4; ++nt) {
      FragU v0, v1;
      v0.u = *(const uint4*)&VB[kvOff0[nt]];
      v1.u = *(const uint4*)&VB[kvOff1[nt]];
      o[nt] = __builtin_amdgcn_mfma_f32_16x16x32_f16(v0.h, aP0.h, o[nt], 0, 0, 0);
      o[nt] = __builtin_amdgcn_mfma_f32_16x16x32_f16(v1.h, aP1.h, o[nt], 0, 0, 0);
    }

    asm volatile("s_waitcnt lgkmcnt(0)" ::: "memory");  // V reads drained
    asm volatile("s_barrier" ::: "memory");   // VB free
    if (more) {
      const ushort* pv = vgB + (size_t)chn * kChunkElems;
      gld16(pv, vDst0);
      gld16(pv + 512, vDst0 + 1024);
    }
  }

  // ---- row-sum reduce across the 4 quad partners (q = l15 fixed per lane)
  rsum += __shfl_xor(rsum, 16, 64);
  rsum += __shfl_xor(rsum, 32, 64);
  const float inv = 1.0f / rsum;

  // ---- epilogue: lane holds one token's row (q = wv*16 + l15); store ao
  // as a single f16 plane straight from registers, 8B per nt.
  const int trg = wv * 16 + l15;
  const int hp = cy * 8 + (trg >> 3);
  const int wp = cx * 8 + (trg & 7);
  const size_t obase = ((size_t)b * kHW + hp * 64 + wp) * (size_t)kC + head * 64;

#pragma unroll
  for (int nt = 0; nt < 4; ++nt) {
    float v0 = o[nt][0] * inv;
    float v1 = o[nt][1] * inv;
    float v2 = o[nt][2] * inv;
    float v3 = o[nt][3] * inv;
    *(ushort4*)(ao + obase + nt * 16 + quad * 4) =
        make_ushort4(f16rn(v0), f16rn(v1), f16rn(v2), f16rn(v3));
  }
}

// ---------------------------------------------------------------------------
// Kernel 3: output projection, single-plane f16 MFMA, 128x128 tile,
// SINGLE-BUFFER + REGISTER PRELOAD (same transform as qkv). LDS 32KB.
// ---------------------------------------------------------------------------
__global__ __launch_bounds__(256)
void proj_mfma_kernel(const ushort* __restrict__ ao,
                      const ushort* __restrict__ wp,
                      const float* __restrict__ bproj,
                      float* __restrict__ out)
{
  __shared__ __align__(16) ushort As[128 * 64];   // wproj 16KB
  __shared__ __align__(16) ushort Bs[128 * 64];   // ao 16KB

  const int tid  = threadIdx.x;
  const int lane = tid & 63;
  const int wv   = tid >> 6;
  const int quad = lane >> 4;
  const int l15  = lane & 15;
  const int wm = wv & 1, wn = wv >> 1;
  const int n0g = blockIdx.x * 128;   // global t (batch-fused, 0..16383)
  const int m0  = blockIdx.y * 128;   // c
  const int b   = n0g >> 12;
  const int tl0 = n0g & 4095;

  auto stage = [&](int k0) {
#pragma unroll
    for (int ii = 0; ii < 4; ++ii) {
      int i = wv * 4 + ii;
      int m = i * 8 + (lane >> 3);
      int gch = (lane & 7) ^ (m & 7);
      gld16(wp + (size_t)(m0 + m) * kC + k0 + gch * 8, (char*)As + i * 1024);
      gld16(ao + (size_t)(n0g + m) * kC + k0 + gch * 8, (char*)Bs + i * 1024);
    }
  };

  f32x4 acc[4][4];
#pragma unroll
  for (int i = 0; i < 4; ++i)
#pragma unroll
    for (int j = 0; j < 4; ++j) acc[i][j] = (f32x4){0.f, 0.f, 0.f, 0.f};

  stage(0);

  for (int kt = 0; kt < 8; ++kt) {
    asm volatile("s_waitcnt vmcnt(0)" ::: "memory");
    asm volatile("s_barrier" ::: "memory");

    FragU a0[4], a1[4], b0[4], b1[4];
#pragma unroll
    for (int mi = 0; mi < 4; ++mi) {
      int mr = wm * 64 + mi * 16 + l15;
      int sw = mr & 7;
      a0[mi].u = *(const uint4*)&As[mr * 64 + ((quad ^ sw) * 8)];
      a1[mi].u = *(const uint4*)&As[mr * 64 + (((4 + quad) ^ sw) * 8)];
    }
#pragma unroll
    for (int ni = 0; ni < 4; ++ni) {
      int nr = wn * 64 + ni * 16 + l15;
      int sw = nr & 7;
      b0[ni].u = *(const uint4*)&Bs[nr * 64 + ((quad ^ sw) * 8)];
      b1[ni].u = *(const uint4*)&Bs[nr * 64 + (((4 + quad) ^ sw) * 8)];
    }
    asm volatile("s_waitcnt lgkmcnt(0)" ::: "memory");
    asm volatile("s_barrier" ::: "memory");

    if (kt < 7) stage((kt + 1) * 64);

#pragma unroll
    for (int mi = 0; mi < 4; ++mi)
#pragma unroll
      for (int ni = 0; ni < 4; ++ni)
        acc[mi][ni] = __builtin_amdgcn_mfma_f32_16x16x32_f16(a0[mi].h, b0[ni].h, acc[mi][ni], 0, 0, 0);
#pragma unroll
    for (int mi = 0; mi < 4; ++mi)
#pragma unroll
      for (int ni = 0; ni < 4; ++ni)
        acc[mi][ni] = __builtin_amdgcn_mfma_f32_16x16x32_f16(a1[mi].h, b1[ni].h, acc[mi][ni], 0, 0, 0);
  }

#pragma unroll
  for (int mi = 0; mi < 4; ++mi)
#pragma unroll
    for (int r = 0; r < 4; ++r) {
      int c = m0 + wm * 64 + mi * 16 + quad * 4 + r;
      float bias = bproj[c];
      size_t rowb = ((size_t)b * kC + c) * (size_t)kHW + tl0 + wn * 64;
#pragma unroll
      for (int ni = 0; ni < 4; ++ni)
        out[rowb + ni * 16 + l15] = acc[mi][ni][r] + bias;
    }
}

}  // namespace

extern "C" void kernel_launch(void* const* d_in, const int* in_sizes, int n_in,
                              void* d_out, int out_size, void* d_ws, size_t ws_size,
                              hipStream_t stream)
{
  const float* x     = (const float*)d_in[0];
  const float* wqkv  = (const float*)d_in[1];
  const float* bqkv  = (const float*)d_in[2];
  const float* wproj = (const float*)d_in[3];
  const float* bproj = (const float*)d_in[4];
  float* out = (float*)d_out;

  const size_t seg = (size_t)2048 * kChunkElems;  // 8,388,608 elems
  ushort* base = (ushort*)d_ws;
  ushort* qb = base + 0 * seg;
  ushort* kb = base + 1 * seg;
  ushort* vb = base + 2 * seg;
  ushort* xt = base + 3 * seg;
  ushort* ao = xt;                       // alias (xt dead after qkv GEMM)
  ushort* wp16 = base + 4 * seg;         // free slot (old ao_lo, dead since r7)
  ushort* wqh = base + 5 * seg;          // 1536*512 = 786432 elems (f16)

  convw16_kernel<<<dim3(512), 256, 0, stream>>>(wqkv, wqh, wproj, wp16);
  convx_kernel<<<dim3(64, 8, 4), 256, 0, stream>>>(x, xt);
  qkv_mfma_kernel<<<dim3(32, 12, 4), 256, 0, stream>>>(xt, wqh, bqkv,
                                                       qb, kb, vb);
  attn_mfma_kernel<<<dim3(2048), 256, 0, stream>>>(qb, kb, vb, ao);
  proj_mfma_kernel<<<dim3(128, 4), 256, 0, stream>>>(ao, wp16, bproj, out);
}